// Round 1
// baseline (444.340 us; speedup 1.0000x reference)
//
#include <hip/hip_runtime.h>
#include <hip/hip_bf16.h>
#include <stdint.h>

#define NE   64
#define DIM  1024
#define HID  512
#define TPE  1024   // tokens per expert (uniform in this problem)

typedef __attribute__((ext_vector_type(8)))  __bf16          bf16x8;
typedef __attribute__((ext_vector_type(16))) float           f32x16;
typedef __attribute__((ext_vector_type(8)))  unsigned short  ushort8_t;
typedef __attribute__((ext_vector_type(4)))  unsigned short  ushort4_t;
typedef __attribute__((ext_vector_type(4)))  float           float4_t;

__device__ __forceinline__ unsigned short f2bf(float f) {
  return __builtin_bit_cast(unsigned short, static_cast<__bf16>(f));  // RNE hw cvt
}
__device__ __forceinline__ float bf2f(unsigned short u) {
  unsigned int x = ((unsigned int)u) << 16;
  return __builtin_bit_cast(float, x);
}
__device__ __forceinline__ ushort4_t pack4(float4_t v) {
  ushort4_t r;
  r[0] = f2bf(v[0]); r[1] = f2bf(v[1]); r[2] = f2bf(v[2]); r[3] = f2bf(v[3]);
  return r;
}

// LDS row stride = 40 bf16 (80 B). 80/16 = 5 (odd) -> b128 frag reads at
// byte r*80 + ks*16 hit bank-slot (5r+ks)%8: even spread, ~conflict-free.
#define LDK 40

// ---------------------------------------------------------------------------
// Phase 1: H[t, j] = silu(x_t . w1[e][j]) * (x_t . w3[e][j])   (bf16 out)
// 128x128 tile, BK=32, 256 thr = 4 waves (2x2) of 64x64, dual acc.
// ---------------------------------------------------------------------------
#define P1_NKT (DIM / 32)

__global__ __launch_bounds__(256, 2) void p1_kernel(
    const float* __restrict__ X, const float* __restrict__ W1,
    const float* __restrict__ W3, unsigned short* __restrict__ H) {
  __shared__ __align__(16) unsigned short lA [2][128 * LDK];
  __shared__ __align__(16) unsigned short lB1[2][128 * LDK];
  __shared__ __align__(16) unsigned short lB3[2][128 * LDK];

  const int bid = blockIdx.x;
  const int e   = bid >> 5;          // 32 tiles / expert
  const int tm  = (bid >> 2) & 7;    // 8 token tiles
  const int tn  = bid & 3;           // 4 hid tiles
  const int t   = threadIdx.x;

  const float* gA  = X  + (size_t)(e * TPE + tm * 128) * DIM;
  const float* gB1 = W1 + ((size_t)e * HID + tn * 128) * DIM;
  const float* gB3 = W3 + ((size_t)e * HID + tn * 128) * DIM;

  float4_t ra[4], rb1[4], rb3[4];

  auto load_tile = [&](int kt) {
#pragma unroll
    for (int i = 0; i < 4; ++i) {
      const int f = t + 256 * i;          // flat float4 index, fully coalesced
      const int row = f >> 3, c4 = f & 7; // 8 float4 per 32-float row
      const size_t off = (size_t)row * DIM + kt * 32 + c4 * 4;
      ra [i] = *reinterpret_cast<const float4_t*>(gA  + off);
      rb1[i] = *reinterpret_cast<const float4_t*>(gB1 + off);
      rb3[i] = *reinterpret_cast<const float4_t*>(gB3 + off);
    }
  };
  auto store_tile = [&](int buf) {
#pragma unroll
    for (int i = 0; i < 4; ++i) {
      const int f = t + 256 * i;
      const int row = f >> 3, c4 = f & 7;
      const int idx = row * LDK + c4 * 4;
      *reinterpret_cast<ushort4_t*>(&lA [buf][idx]) = pack4(ra [i]);
      *reinterpret_cast<ushort4_t*>(&lB1[buf][idx]) = pack4(rb1[i]);
      *reinterpret_cast<ushort4_t*>(&lB3[buf][idx]) = pack4(rb3[i]);
    }
  };

  const int lane = t & 63;
  const int wv   = t >> 6;
  const int wr   = wv >> 1, wc = wv & 1;   // 2x2 waves, 64x64 each
  const int lr   = lane & 31;              // A row / B col within 32
  const int ks   = lane >> 5;              // k half (8 elems)

  const int aoff0 = (wr * 64 + lr) * LDK + ks * 8;
  const int boff0 = (wc * 64 + lr) * LDK + ks * 8;

  f32x16 acc1[2][2], acc3[2][2];
#pragma unroll
  for (int m = 0; m < 2; ++m)
#pragma unroll
    for (int n = 0; n < 2; ++n)
#pragma unroll
      for (int i = 0; i < 16; ++i) { acc1[m][n][i] = 0.f; acc3[m][n][i] = 0.f; }

  load_tile(0);
  for (int kt = 0; kt < P1_NKT; ++kt) {
    const int buf = kt & 1;
    store_tile(buf);           // cvt fp32->bf16, write LDS (waits on loads)
    __syncthreads();           // single barrier/iter: dbuf makes it safe
    if (kt + 1 < P1_NKT) load_tile(kt + 1);  // in flight during MFMAs
#pragma unroll
    for (int kk = 0; kk < 2; ++kk) {         // BK=32 = 2 x K16
      bf16x8 a[2], b1[2], b3[2];
#pragma unroll
      for (int m = 0; m < 2; ++m)
        a[m] = __builtin_bit_cast(bf16x8, *reinterpret_cast<const ushort8_t*>(
                   &lA[buf][aoff0 + m * (32 * LDK) + kk * 16]));
#pragma unroll
      for (int n = 0; n < 2; ++n) {
        b1[n] = __builtin_bit_cast(bf16x8, *reinterpret_cast<const ushort8_t*>(
                    &lB1[buf][boff0 + n * (32 * LDK) + kk * 16]));
        b3[n] = __builtin_bit_cast(bf16x8, *reinterpret_cast<const ushort8_t*>(
                    &lB3[buf][boff0 + n * (32 * LDK) + kk * 16]));
      }
#pragma unroll
      for (int m = 0; m < 2; ++m)
#pragma unroll
        for (int n = 0; n < 2; ++n) {
          acc1[m][n] = __builtin_amdgcn_mfma_f32_32x32x16_bf16(a[m], b1[n], acc1[m][n], 0, 0, 0);
          acc3[m][n] = __builtin_amdgcn_mfma_f32_32x32x16_bf16(a[m], b3[n], acc3[m][n], 0, 0, 0);
        }
    }
  }

  // epilogue: silu(a)*b -> bf16 H.  C/D 32x32 layout: col=lane&31,
  // row=(reg&3)+8*(reg>>2)+4*(lane>>5)   [m74/m101 verified]
  const int tokBase = e * TPE + tm * 128 + wr * 64;
  const int hidBase = tn * 128 + wc * 64;
#pragma unroll
  for (int m = 0; m < 2; ++m)
#pragma unroll
    for (int n = 0; n < 2; ++n)
#pragma unroll
      for (int r = 0; r < 16; ++r) {
        const int rr  = (r & 3) + 8 * (r >> 2) + 4 * ks;
        const int tok = tokBase + m * 32 + rr;
        const int hid = hidBase + n * 32 + lr;
        const float av = bf2f(f2bf(acc1[m][n][r]));   // match ref bf16 rounding
        const float bv = bf2f(f2bf(acc3[m][n][r]));
        const float s  = av / (1.0f + __expf(-av));   // silu
        H[(size_t)tok * HID + hid] = f2bf(s * bv);
      }
}

// ---------------------------------------------------------------------------
// Phase 2: OUT[t, d] = h_t . w2[e][d]   (fp32 out, bf16-rounded like ref)
// ---------------------------------------------------------------------------
#define P2_NKT (HID / 32)

__global__ __launch_bounds__(256, 2) void p2_kernel(
    const unsigned short* __restrict__ Hin, const float* __restrict__ W2,
    float* __restrict__ OUT) {
  __shared__ __align__(16) unsigned short lA[2][128 * LDK];
  __shared__ __align__(16) unsigned short lB[2][128 * LDK];

  const int bid = blockIdx.x;
  const int e   = bid >> 6;          // 64 tiles / expert
  const int tm  = (bid >> 3) & 7;
  const int tn  = bid & 7;
  const int t   = threadIdx.x;

  const unsigned short* gA = Hin + (size_t)(e * TPE + tm * 128) * HID;
  const float*          gB = W2  + ((size_t)e * DIM + tn * 128) * HID;

  ushort8_t ra[2];
  float4_t  rb[4];

  auto load_tile = [&](int kt) {
#pragma unroll
    for (int i = 0; i < 2; ++i) {
      const int f = t + 256 * i;            // flat 8-bf16 chunk index (512)
      const int row = f >> 2, c8 = f & 3;
      ra[i] = *reinterpret_cast<const ushort8_t*>(gA + (size_t)row * HID + kt * 32 + c8 * 8);
    }
#pragma unroll
    for (int i = 0; i < 4; ++i) {
      const int f = t + 256 * i;
      const int row = f >> 3, c4 = f & 7;
      rb[i] = *reinterpret_cast<const float4_t*>(gB + (size_t)row * HID + kt * 32 + c4 * 4);
    }
  };
  auto store_tile = [&](int buf) {
#pragma unroll
    for (int i = 0; i < 2; ++i) {
      const int f = t + 256 * i;
      const int row = f >> 2, c8 = f & 3;
      *reinterpret_cast<ushort8_t*>(&lA[buf][row * LDK + c8 * 8]) = ra[i];
    }
#pragma unroll
    for (int i = 0; i < 4; ++i) {
      const int f = t + 256 * i;
      const int row = f >> 3, c4 = f & 7;
      *reinterpret_cast<ushort4_t*>(&lB[buf][row * LDK + c4 * 4]) = pack4(rb[i]);
    }
  };

  const int lane = t & 63;
  const int wv   = t >> 6;
  const int wr   = wv >> 1, wc = wv & 1;
  const int lr   = lane & 31;
  const int ks   = lane >> 5;

  const int aoff0 = (wr * 64 + lr) * LDK + ks * 8;
  const int boff0 = (wc * 64 + lr) * LDK + ks * 8;

  f32x16 acc[2][2];
#pragma unroll
  for (int m = 0; m < 2; ++m)
#pragma unroll
    for (int n = 0; n < 2; ++n)
#pragma unroll
      for (int i = 0; i < 16; ++i) acc[m][n][i] = 0.f;

  load_tile(0);
  for (int kt = 0; kt < P2_NKT; ++kt) {
    const int buf = kt & 1;
    store_tile(buf);
    __syncthreads();
    if (kt + 1 < P2_NKT) load_tile(kt + 1);
#pragma unroll
    for (int kk = 0; kk < 2; ++kk) {
      bf16x8 a[2], b[2];
#pragma unroll
      for (int m = 0; m < 2; ++m)
        a[m] = __builtin_bit_cast(bf16x8, *reinterpret_cast<const ushort8_t*>(
                   &lA[buf][aoff0 + m * (32 * LDK) + kk * 16]));
#pragma unroll
      for (int n = 0; n < 2; ++n)
        b[n] = __builtin_bit_cast(bf16x8, *reinterpret_cast<const ushort8_t*>(
                   &lB[buf][boff0 + n * (32 * LDK) + kk * 16]));
#pragma unroll
      for (int m = 0; m < 2; ++m)
#pragma unroll
        for (int n = 0; n < 2; ++n)
          acc[m][n] = __builtin_amdgcn_mfma_f32_32x32x16_bf16(a[m], b[n], acc[m][n], 0, 0, 0);
    }
  }

  const int tokBase = e * TPE + tm * 128 + wr * 64;
  const int dBase   = tn * 128 + wc * 64;
#pragma unroll
  for (int m = 0; m < 2; ++m)
#pragma unroll
    for (int n = 0; n < 2; ++n)
#pragma unroll
      for (int r = 0; r < 16; ++r) {
        const int rr  = (r & 3) + 8 * (r >> 2) + 4 * ks;
        const int tok = tokBase + m * 32 + rr;
        const int d   = dBase + n * 32 + lr;
        OUT[(size_t)tok * DIM + d] = bf2f(f2bf(acc[m][n][r]));  // ref casts bf16->f32
      }
}

// ---------------------------------------------------------------------------
extern "C" void kernel_launch(void* const* d_in, const int* in_sizes, int n_in,
                              void* d_out, int out_size, void* d_ws, size_t ws_size,
                              hipStream_t stream) {
  (void)in_sizes; (void)n_in; (void)out_size; (void)ws_size;
  const float* X  = (const float*)d_in[0];
  const float* W1 = (const float*)d_in[1];
  const float* W2 = (const float*)d_in[2];
  const float* W3 = (const float*)d_in[3];
  // d_in[4] = num_tokens_per_expert: uniform 1024/expert in this problem.

  unsigned short* H = (unsigned short*)d_ws;   // 65536 x 512 bf16 = 64 MiB
  float* OUT = (float*)d_out;

  p1_kernel<<<dim3(NE * 8 * 4), dim3(256), 0, stream>>>(X, W1, W3, H);
  p2_kernel<<<dim3(NE * 8 * 8), dim3(256), 0, stream>>>(H, W2, OUT);
}

// Round 2
// 424.701 us; speedup vs baseline: 1.0462x; 1.0462x over previous
//
#include <hip/hip_runtime.h>
#include <hip/hip_bf16.h>
#include <stdint.h>

#define NE   64
#define DIM  1024
#define HID  512
#define TPE  1024   // tokens per expert (uniform in this problem)

typedef __attribute__((ext_vector_type(8)))  __bf16          bf16x8;
typedef __attribute__((ext_vector_type(16))) float           f32x16;
typedef __attribute__((ext_vector_type(8)))  unsigned short  ushort8_t;
typedef __attribute__((ext_vector_type(4)))  float           float4_t;

__device__ __forceinline__ unsigned short f2bf(float f) {
  return __builtin_bit_cast(unsigned short, static_cast<__bf16>(f));  // RNE hw cvt
}
__device__ __forceinline__ float bf2f(unsigned short u) {
  unsigned int x = ((unsigned int)u) << 16;
  return __builtin_bit_cast(float, x);
}
__device__ __forceinline__ ushort8_t pack8(float4_t a, float4_t b) {
  ushort8_t r;
  r[0] = f2bf(a[0]); r[1] = f2bf(a[1]); r[2] = f2bf(a[2]); r[3] = f2bf(a[3]);
  r[4] = f2bf(b[0]); r[5] = f2bf(b[1]); r[6] = f2bf(b[2]); r[7] = f2bf(b[3]);
  return r;  // compiler emits v_cvt_pk_bf16_f32 pairs (m240: don't hand-write)
}

// LDS row stride = 40 bf16 (80 B). 80/16 = 5 (odd) -> b128 reads at byte
// r*80 + 16k hit 16B-slot (5r+k)%8: even spread over banks, ~conflict-free.
// 40 keeps rows 16B-aligned for ds_read_b128/ds_write_b128.
#define LDK 40

// XCD-aware bijective swizzle: 4096 blocks % 8 == 0.
// Dispatch round-robins blockIdx across 8 XCDs; this gives each XCD a
// contiguous 512-tile chunk (= 8 whole experts) for L2 locality.
__device__ __forceinline__ int xcd_swizzle(int bid, int nwg) {
  return (bid & 7) * (nwg >> 3) + (bid >> 3);
}

// ---------------------------------------------------------------------------
// Phase 1: H[t, j] = silu(x_t . w1[e][j]) * (x_t . w3[e][j])   (bf16 out)
// Block tile 128(M) x 64(N), BK=32, 256 thr = 4 waves (2x2) of 64x32, dual acc.
// LDS 40 KB/block (dbuf), target 4 blocks/CU, regs <= 128.
// ---------------------------------------------------------------------------
#define P1_NKT (DIM / 32)

__global__ __launch_bounds__(256, 4) void p1_kernel(
    const float* __restrict__ X, const float* __restrict__ W1,
    const float* __restrict__ W3, unsigned short* __restrict__ H) {
  __shared__ __align__(16) unsigned short lA [2][128 * LDK];  // 20480 B
  __shared__ __align__(16) unsigned short lB1[2][ 64 * LDK];  // 10240 B
  __shared__ __align__(16) unsigned short lB3[2][ 64 * LDK];  // 10240 B

  const int tile = xcd_swizzle(blockIdx.x, NE * 8 * 8);
  const int e  = tile >> 6;          // 64 tiles / expert
  const int tm = (tile >> 3) & 7;    // 8 token tiles (128 rows)
  const int tn = tile & 7;           // 8 hid tiles (64 cols) — tn inner: X slab hot
  const int t  = threadIdx.x;

  const float* gA  = X  + (size_t)(e * TPE + tm * 128) * DIM;
  const float* gB1 = W1 + ((size_t)e * HID + tn * 64) * DIM;
  const float* gB3 = W3 + ((size_t)e * HID + tn * 64) * DIM;

  // staging regs: A = 2 chunks of 8 floats, B1/B3 = 1 chunk each -> 8 float4
  float4_t ra[2][2], rb1[2], rb3[2];

  // A: 128x32 = 512 chunks-of-8 / 256 thr = 2; chunk c: row c>>2, col (c&3)*8
  // B: 64x32 = 256 chunks / 256 thr = 1
  const int arow0 = t >> 2, acol = (t & 3) * 8;   // chunk0 (chunk1 = +64 rows)
  const int brow  = t >> 2, bcol = (t & 3) * 8;

  auto load_tile = [&](int kt) {
#pragma unroll
    for (int i = 0; i < 2; ++i) {
      const size_t off = (size_t)(arow0 + 64 * i) * DIM + kt * 32 + acol;
      ra[i][0] = *reinterpret_cast<const float4_t*>(gA + off);
      ra[i][1] = *reinterpret_cast<const float4_t*>(gA + off + 4);
    }
    const size_t boff = (size_t)brow * DIM + kt * 32 + bcol;
    rb1[0] = *reinterpret_cast<const float4_t*>(gB1 + boff);
    rb1[1] = *reinterpret_cast<const float4_t*>(gB1 + boff + 4);
    rb3[0] = *reinterpret_cast<const float4_t*>(gB3 + boff);
    rb3[1] = *reinterpret_cast<const float4_t*>(gB3 + boff + 4);
  };
  auto store_tile = [&](int buf) {
#pragma unroll
    for (int i = 0; i < 2; ++i)
      *reinterpret_cast<ushort8_t*>(&lA[buf][(arow0 + 64 * i) * LDK + acol]) =
          pack8(ra[i][0], ra[i][1]);
    *reinterpret_cast<ushort8_t*>(&lB1[buf][brow * LDK + bcol]) = pack8(rb1[0], rb1[1]);
    *reinterpret_cast<ushort8_t*>(&lB3[buf][brow * LDK + bcol]) = pack8(rb3[0], rb3[1]);
  };

  const int lane = t & 63;
  const int wv   = t >> 6;
  const int wr   = wv >> 1, wc = wv & 1;   // 2x2 waves: 64 rows x 32 cols each
  const int lr   = lane & 31;
  const int ks   = lane >> 5;              // k half (8 elems)

  const int aoff0 = (wr * 64 + lr) * LDK + ks * 8;
  const int boff0 = (wc * 32 + lr) * LDK + ks * 8;

  f32x16 acc1[2], acc3[2];
#pragma unroll
  for (int m = 0; m < 2; ++m)
#pragma unroll
    for (int i = 0; i < 16; ++i) { acc1[m][i] = 0.f; acc3[m][i] = 0.f; }

  load_tile(0);
  for (int kt = 0; kt < P1_NKT; ++kt) {
    const int buf = kt & 1;
    store_tile(buf);                         // waits on loads via dependency
    __syncthreads();                         // single barrier/iter (dbuf-safe)
    if (kt + 1 < P1_NKT) load_tile(kt + 1);  // in flight during MFMAs
#pragma unroll
    for (int kk = 0; kk < 2; ++kk) {         // BK=32 = 2 x K16
      bf16x8 a[2], b1, b3;
#pragma unroll
      for (int m = 0; m < 2; ++m)
        a[m] = __builtin_bit_cast(bf16x8, *reinterpret_cast<const ushort8_t*>(
                   &lA[buf][aoff0 + m * (32 * LDK) + kk * 16]));
      b1 = __builtin_bit_cast(bf16x8, *reinterpret_cast<const ushort8_t*>(
               &lB1[buf][boff0 + kk * 16]));
      b3 = __builtin_bit_cast(bf16x8, *reinterpret_cast<const ushort8_t*>(
               &lB3[buf][boff0 + kk * 16]));
#pragma unroll
      for (int m = 0; m < 2; ++m) {
        acc1[m] = __builtin_amdgcn_mfma_f32_32x32x16_bf16(a[m], b1, acc1[m], 0, 0, 0);
        acc3[m] = __builtin_amdgcn_mfma_f32_32x32x16_bf16(a[m], b3, acc3[m], 0, 0, 0);
      }
    }
  }

  // epilogue: silu(a)*b -> bf16 H.  C/D 32x32 layout: col=lane&31,
  // row=(reg&3)+8*(reg>>2)+4*(lane>>5)   [m74/m101 verified]
  const int tokBase = e * TPE + tm * 128 + wr * 64;
  const int hid     = tn * 64 + wc * 32 + lr;
#pragma unroll
  for (int m = 0; m < 2; ++m)
#pragma unroll
    for (int r = 0; r < 16; ++r) {
      const int rr  = (r & 3) + 8 * (r >> 2) + 4 * ks;
      const int tok = tokBase + m * 32 + rr;
      const float av = bf2f(f2bf(acc1[m][r]));   // match ref bf16 rounding
      const float bv = bf2f(f2bf(acc3[m][r]));
      const float s  = av / (1.0f + __expf(-av));
      H[(size_t)tok * HID + hid] = f2bf(s * bv);
    }
}

// ---------------------------------------------------------------------------
// Phase 2: OUT[t, d] = h_t . w2[e][d]   (fp32 out, bf16-rounded like ref)
// Block tile 128x128, BK=32, 4 waves (2x2) of 64x64. LDS 40 KB (dbuf).
// ---------------------------------------------------------------------------
#define P2_NKT (HID / 32)

__global__ __launch_bounds__(256, 4) void p2_kernel(
    const unsigned short* __restrict__ Hin, const float* __restrict__ W2,
    float* __restrict__ OUT) {
  __shared__ __align__(16) unsigned short lA[2][128 * LDK];  // 20480 B
  __shared__ __align__(16) unsigned short lB[2][128 * LDK];  // 20480 B

  const int tile = xcd_swizzle(blockIdx.x, NE * 8 * 8);
  const int e  = tile >> 6;
  const int tm = (tile >> 3) & 7;
  const int tn = tile & 7;
  const int t  = threadIdx.x;

  const unsigned short* gA = Hin + (size_t)(e * TPE + tm * 128) * HID;
  const float*          gB = W2  + ((size_t)e * DIM + tn * 128) * HID;

  ushort8_t ra[2];       // A already bf16: plain copy
  float4_t  rb[2][2];

  const int row0 = t >> 2, col = (t & 3) * 8;   // 128x32: 2 chunks/thread

  auto load_tile = [&](int kt) {
#pragma unroll
    for (int i = 0; i < 2; ++i) {
      ra[i] = *reinterpret_cast<const ushort8_t*>(
          gA + (size_t)(row0 + 64 * i) * HID + kt * 32 + col);
      const size_t off = (size_t)(row0 + 64 * i) * HID + kt * 32 + col;
      rb[i][0] = *reinterpret_cast<const float4_t*>(gB + off);
      rb[i][1] = *reinterpret_cast<const float4_t*>(gB + off + 4);
    }
  };
  auto store_tile = [&](int buf) {
#pragma unroll
    for (int i = 0; i < 2; ++i) {
      const int idx = (row0 + 64 * i) * LDK + col;
      *reinterpret_cast<ushort8_t*>(&lA[buf][idx]) = ra[i];
      *reinterpret_cast<ushort8_t*>(&lB[buf][idx]) = pack8(rb[i][0], rb[i][1]);
    }
  };

  const int lane = t & 63;
  const int wv   = t >> 6;
  const int wr   = wv >> 1, wc = wv & 1;   // 2x2 waves, 64x64 each
  const int lr   = lane & 31;
  const int ks   = lane >> 5;

  const int aoff0 = (wr * 64 + lr) * LDK + ks * 8;
  const int boff0 = (wc * 64 + lr) * LDK + ks * 8;

  f32x16 acc[2][2];
#pragma unroll
  for (int m = 0; m < 2; ++m)
#pragma unroll
    for (int n = 0; n < 2; ++n)
#pragma unroll
      for (int i = 0; i < 16; ++i) acc[m][n][i] = 0.f;

  load_tile(0);
  for (int kt = 0; kt < P2_NKT; ++kt) {
    const int buf = kt & 1;
    store_tile(buf);
    __syncthreads();
    if (kt + 1 < P2_NKT) load_tile(kt + 1);
#pragma unroll
    for (int kk = 0; kk < 2; ++kk) {
      bf16x8 a[2], b[2];
#pragma unroll
      for (int m = 0; m < 2; ++m)
        a[m] = __builtin_bit_cast(bf16x8, *reinterpret_cast<const ushort8_t*>(
                   &lA[buf][aoff0 + m * (32 * LDK) + kk * 16]));
#pragma unroll
      for (int n = 0; n < 2; ++n)
        b[n] = __builtin_bit_cast(bf16x8, *reinterpret_cast<const ushort8_t*>(
                   &lB[buf][boff0 + n * (32 * LDK) + kk * 16]));
#pragma unroll
      for (int m = 0; m < 2; ++m)
#pragma unroll
        for (int n = 0; n < 2; ++n)
          acc[m][n] = __builtin_amdgcn_mfma_f32_32x32x16_bf16(a[m], b[n], acc[m][n], 0, 0, 0);
    }
  }

  const int tokBase = e * TPE + tm * 128 + wr * 64;
  const int dBase   = tn * 128 + wc * 64;
#pragma unroll
  for (int m = 0; m < 2; ++m)
#pragma unroll
    for (int n = 0; n < 2; ++n)
#pragma unroll
      for (int r = 0; r < 16; ++r) {
        const int rr  = (r & 3) + 8 * (r >> 2) + 4 * ks;
        const int tok = tokBase + m * 32 + rr;
        const int d   = dBase + n * 32 + lr;
        OUT[(size_t)tok * DIM + d] = bf2f(f2bf(acc[m][n][r]));  // ref bf16->f32
      }
}

// ---------------------------------------------------------------------------
extern "C" void kernel_launch(void* const* d_in, const int* in_sizes, int n_in,
                              void* d_out, int out_size, void* d_ws, size_t ws_size,
                              hipStream_t stream) {
  (void)in_sizes; (void)n_in; (void)out_size; (void)ws_size;
  const float* X  = (const float*)d_in[0];
  const float* W1 = (const float*)d_in[1];
  const float* W2 = (const float*)d_in[2];
  const float* W3 = (const float*)d_in[3];
  // d_in[4] = num_tokens_per_expert: uniform 1024/expert in this problem.

  unsigned short* H = (unsigned short*)d_ws;   // 65536 x 512 bf16 = 64 MiB
  float* OUT = (float*)d_out;

  p1_kernel<<<dim3(NE * 8 * 8), dim3(256), 0, stream>>>(X, W1, W3, H);
  p2_kernel<<<dim3(NE * 8 * 8), dim3(256), 0, stream>>>(H, W2, OUT);
}